// Round 3
// baseline (539.622 us; speedup 1.0000x reference)
//
#include <hip/hip_runtime.h>
#include <hip/hip_bf16.h>
#include <stdint.h>

// ---------------------------------------------------------------------------
// LoRALinear (fp32 in / fp32 out):
//   C[M,N] = X[M,K] @ W[N,K]^T + bias[N] + 2.0 * (X @ A[R,K]^T) @ B[N,R]^T
// M=8192, N=4096, K=4096, R=16.
//
// Round-6: two changes driven by round-2 counters (MfmaUtil 50%, conflicts 0,
// wall = MFMA-pipe + LDS-pipe cycles back-to-back; ~270us of total invisible
// in top-5 = uncoalesced pack kernels hidden behind gemm replays):
//  (a) 32x32x16 MFMA geometry: 2495 vs 2075 TF ceiling (-17% MFMA-pipe time),
//      2x fewer MFMA instrs, same LDS bytes, same acc VGPR count. Packed
//      32x16 blocks keep gload_lds linear + ds_read conflict-free.
//  (b) coalesced pack kernels: 2 lanes/row 64-B reads (4-wave WG tiles
//      256 B/row), fragment transpose via 4 in-register __shfl.
// Schedule unchanged (proven): 4-deep LDS circular, dist-3 prefetch, counted
// vmcnt(6)/lgkm(6) never 0 in loop, 1 barrier/phase, setprio, XCD swizzle.
// ---------------------------------------------------------------------------

typedef __bf16 bf16x8 __attribute__((ext_vector_type(8)));
typedef __bf16 bf16x4 __attribute__((ext_vector_type(4)));
typedef float f32x4 __attribute__((ext_vector_type(4)));
typedef float f32x16 __attribute__((ext_vector_type(16)));
typedef int i32x4 __attribute__((ext_vector_type(4)));

#define LORA_R 16

__device__ __forceinline__ void async_copy16(const void* g, void* l) {
  __builtin_amdgcn_global_load_lds(
      (const __attribute__((address_space(1))) void*)g,
      (__attribute__((address_space(3))) void*)l, 16, 0, 0);
}

// ---------------------------------------------------------------------------
// Packed operand layout (32x32x16 MFMA): 32 rows x 16 k blocks of 1 KB.
// Block (rb, kblk) at byte offset (rb*(K/16)+kblk)*1024. Lane l's 16 B:
//   row = rb*32 + (l&31), k = kblk*16 + (l>>5)*8 + e   (A/B fragment order)
// ---------------------------------------------------------------------------

// Coalesced pack: wave reads 32 rows x 16 k as 2 lanes/row (64 B per row;
// 4-wave WG covers 256 B/row contiguous), then in-register shfl transpose.
__global__ __launch_bounds__(256) void pack_x_kernel(
    const float* __restrict__ X, __hip_bfloat16* __restrict__ Xp, int K) {
  const int lane = threadIdx.x & 63;
  const int wave = threadIdx.x >> 6;
  const int nkblk = K >> 4;
  const int kblk = blockIdx.x * 4 + wave;
  const int rb = blockIdx.y;
  const int srow = rb * 32 + (lane >> 1);
  const int scol = kblk * 16 + (lane & 1) * 8;
  const float* src = X + (size_t)srow * K + scol;
  f32x4 v0 = *(const f32x4*)src;
  f32x4 v1 = *(const f32x4*)(src + 4);
  bf16x8 o;
#pragma unroll
  for (int j = 0; j < 4; ++j) { o[j] = (__bf16)v0[j]; o[4 + j] = (__bf16)v1[j]; }
  // dest lane l wants (row=l&31, khalf=l>>5) -> src lane ((l&31)<<1)|(l>>5)
  const int s = ((lane & 31) << 1) | (lane >> 5);
  i32x4 wv = __builtin_bit_cast(i32x4, o);
  i32x4 rv;
#pragma unroll
  for (int d = 0; d < 4; ++d) rv[d] = __shfl(wv[d], s, 64);
  *(i32x4*)((char*)Xp + ((size_t)(rb * nkblk + kblk) << 10) + (lane << 4)) = rv;
}

// Same structure + LoRA fold: W'[n,k] = W[n,k] + 2 * sum_r B[n,r] A[r,k].
__global__ __launch_bounds__(256) void foldpack_w_kernel(
    const float* __restrict__ W, const float* __restrict__ A,
    const float* __restrict__ Bl, __hip_bfloat16* __restrict__ Wp, int K) {
  const int lane = threadIdx.x & 63;
  const int wave = threadIdx.x >> 6;
  const int nkblk = K >> 4;
  const int kblk = blockIdx.x * 4 + wave;
  const int nb = blockIdx.y;
  const int n = nb * 32 + (lane >> 1);
  const int col = kblk * 16 + (lane & 1) * 8;
  float res[8];
  {
    f32x4 w0 = *(const f32x4*)(W + (size_t)n * K + col);
    f32x4 w1 = *(const f32x4*)(W + (size_t)n * K + col + 4);
#pragma unroll
    for (int j = 0; j < 4; ++j) { res[j] = w0[j]; res[4 + j] = w1[j]; }
  }
#pragma unroll
  for (int r = 0; r < LORA_R; ++r) {
    const float b2 = 2.0f * Bl[n * LORA_R + r];  // SCALING = 2.0
    f32x4 a0 = *(const f32x4*)(A + (size_t)r * K + col);
    f32x4 a1 = *(const f32x4*)(A + (size_t)r * K + col + 4);
#pragma unroll
    for (int j = 0; j < 4; ++j) { res[j] += b2 * a0[j]; res[4 + j] += b2 * a1[j]; }
  }
  bf16x8 o;
#pragma unroll
  for (int j = 0; j < 8; ++j) o[j] = (__bf16)res[j];
  const int s = ((lane & 31) << 1) | (lane >> 5);
  i32x4 wv = __builtin_bit_cast(i32x4, o);
  i32x4 rv;
#pragma unroll
  for (int d = 0; d < 4; ++d) rv[d] = __shfl(wv[d], s, 64);
  *(i32x4*)((char*)Wp + ((size_t)(nb * nkblk + kblk) << 10) + (lane << 4)) = rv;
}

// ---------------------------------------------------------------------------
// Pipelined 256x256 GEMM, 8 waves (2M x 4N), per-wave 128x64 as 4x2 grid of
// 32x32 tiles, BK=32 (2 k-steps of 16). LDS: 4 circular bufs x (16KB A +
// 16KB B). Per tile: ph0 {read kb1 set, stage A(t+3), lgkm(6), 8 MFMA kb0,
// vmcnt(6), bar}; ph1 {read next-tile kb0 set, stage B(t+3), lgkm(6),
// 8 MFMA kb1, bar}.
// ---------------------------------------------------------------------------
#define RD6(AV, BV, KB, OFS)                                                  \
  AV[0] = *(const bf16x8*)(ldsRdA + (OFS) + (KB) * 1024 + 0 * 2048);          \
  AV[1] = *(const bf16x8*)(ldsRdA + (OFS) + (KB) * 1024 + 1 * 2048);          \
  AV[2] = *(const bf16x8*)(ldsRdA + (OFS) + (KB) * 1024 + 2 * 2048);          \
  AV[3] = *(const bf16x8*)(ldsRdA + (OFS) + (KB) * 1024 + 3 * 2048);          \
  BV[0] = *(const bf16x8*)(ldsRdB + (OFS) + (KB) * 1024 + 0 * 2048);          \
  BV[1] = *(const bf16x8*)(ldsRdB + (OFS) + (KB) * 1024 + 1 * 2048);

#define MFMA8(AV, BV)                                                         \
  acc[0][0] = __builtin_amdgcn_mfma_f32_32x32x16_bf16(AV[0], BV[0], acc[0][0], 0, 0, 0); \
  acc[0][1] = __builtin_amdgcn_mfma_f32_32x32x16_bf16(AV[0], BV[1], acc[0][1], 0, 0, 0); \
  acc[1][0] = __builtin_amdgcn_mfma_f32_32x32x16_bf16(AV[1], BV[0], acc[1][0], 0, 0, 0); \
  acc[1][1] = __builtin_amdgcn_mfma_f32_32x32x16_bf16(AV[1], BV[1], acc[1][1], 0, 0, 0); \
  acc[2][0] = __builtin_amdgcn_mfma_f32_32x32x16_bf16(AV[2], BV[0], acc[2][0], 0, 0, 0); \
  acc[2][1] = __builtin_amdgcn_mfma_f32_32x32x16_bf16(AV[2], BV[1], acc[2][1], 0, 0, 0); \
  acc[3][0] = __builtin_amdgcn_mfma_f32_32x32x16_bf16(AV[3], BV[0], acc[3][0], 0, 0, 0); \
  acc[3][1] = __builtin_amdgcn_mfma_f32_32x32x16_bf16(AV[3], BV[1], acc[3][1], 0, 0, 0);

#define STAGE_A(T, SLOT)                                                      \
  async_copy16(aSrc + ((size_t)(T) << 11), ldsA + (SLOT));                    \
  async_copy16(aSrc + ((size_t)(T) << 11) + 1024, ldsA + (SLOT) + 1024);

#define STAGE_B(T, SLOT)                                                      \
  async_copy16(bSrc + ((size_t)(T) << 11), ldsB + (SLOT));                    \
  async_copy16(bSrc + ((size_t)(T) << 11) + 1024, ldsB + (SLOT) + 1024);

#define SBAR() __builtin_amdgcn_sched_barrier(0)

__global__ __launch_bounds__(512, 2) void gemm_pipelined(
    const __hip_bfloat16* __restrict__ Xp,  // packed [M/32][K/16] blocks
    const __hip_bfloat16* __restrict__ Wp,  // packed [N/32][K/16] blocks
    const float* __restrict__ bias,
    float* __restrict__ Out, int M, int N, int K) {
  __shared__ __align__(16) char lds[131072];

  const int tid = threadIdx.x;
  const int lane = tid & 63;
  const int wave = tid >> 6;
  const int wm = wave >> 2;  // 0..1
  const int wn = wave & 3;   // 0..3

  // Bijective XCD-aware swizzle (gridDim.x = 512, % 8 == 0).
  const int nwg = gridDim.x;
  const int bid = blockIdx.x;
  const int swz = (bid & 7) * (nwg >> 3) + (bid >> 3);
  const int ntn = N >> 8;  // 16
  const int tm = swz / ntn;
  const int tn = swz - tm * ntn;

  const int nkblk = K >> 4;  // 256 packed k-blocks
  const int nt = K >> 5;     // 128 K-tiles (BK=32)

  // Wave w stages A rowblock tm*8+w and B colblock tn*8+w (2 KB each/tile).
  const char* aSrc = (const char*)Xp +
      ((size_t)((tm << 3) + wave) * nkblk << 10) + (lane << 4);
  const char* bSrc = (const char*)Wp +
      ((size_t)((tn << 3) + wave) * nkblk << 10) + (lane << 4);

  char* ldsA = lds + (wave << 11);           // slot (rb=w)*2048
  char* ldsB = lds + 16384 + (wave << 11);
  // A frag (i,kb): wave base + (i*2+kb)*1024; wm selects rowblocks wm*4..+4.
  const char* ldsRdA = lds + (wm << 13) + (lane << 4);
  const char* ldsRdB = lds + 16384 + (wn << 12) + (lane << 4);

  f32x16 acc[4][2];
#pragma unroll
  for (int i = 0; i < 4; ++i)
#pragma unroll
    for (int j = 0; j < 2; ++j) acc[i][j] = (f32x16)(0.f);

  // Prologue: stage tiles 0,1,2 into bufs 0,1,2 (12 loads/wave).
#pragma unroll
  for (int pt = 0; pt < 3; ++pt) {
    const int bo = pt << 15;
    STAGE_A(pt, bo);
    STAGE_B(pt, bo);
  }
  asm volatile("s_waitcnt vmcnt(8)" ::: "memory");  // tile 0 landed
  __builtin_amdgcn_s_barrier();
  SBAR();

  bf16x8 aP[4], bP[2], aQ[4], bQ[2];
  RD6(aP, bP, 0, 0);  // tile 0, k-step 0

  for (int t = 0; t + 4 <= nt; ++t) {
    const int ofs = (t & 3) << 15;
    const int ofsN = ((t + 1) & 3) << 15;
    const int s3 = ((t + 3) & 3) << 15;

    // ---- ph0: consume kb0 (P); read kb1 (Q); stage A(t+3) ----
    RD6(aQ, bQ, 1, ofs);
    STAGE_A(t + 3, s3);
    asm volatile("s_waitcnt lgkmcnt(6)" ::: "memory");  // P ready
    SBAR();
    __builtin_amdgcn_s_setprio(1);
    MFMA8(aP, bP);
    __builtin_amdgcn_s_setprio(0);
    asm volatile("s_waitcnt vmcnt(6)" ::: "memory");  // tile t+1 landed
    __builtin_amdgcn_s_barrier();
    SBAR();

    // ---- ph1: consume kb1 (Q); read next-tile kb0 (P); stage B(t+3) ----
    RD6(aP, bP, 0, ofsN);
    STAGE_B(t + 3, s3);
    asm volatile("s_waitcnt lgkmcnt(6)" ::: "memory");  // Q ready
    SBAR();
    __builtin_amdgcn_s_setprio(1);
    MFMA8(aQ, bQ);
    __builtin_amdgcn_s_setprio(0);
    __builtin_amdgcn_s_barrier();
    SBAR();
  }

  // Drain: all tiles staged; compute last 3 plainly (compiler-managed waits).
  asm volatile("s_waitcnt vmcnt(0)" ::: "memory");
  __builtin_amdgcn_s_barrier();
  SBAR();
  for (int t = nt - 3; t < nt; ++t) {
    const int ofs = (t & 3) << 15;
    bf16x8 aT[4][2], bT[2][2];
#pragma unroll
    for (int i = 0; i < 4; ++i)
#pragma unroll
      for (int kb = 0; kb < 2; ++kb)
        aT[i][kb] = *(const bf16x8*)(ldsRdA + ofs + (i * 2 + kb) * 1024);
#pragma unroll
    for (int j = 0; j < 2; ++j)
#pragma unroll
      for (int kb = 0; kb < 2; ++kb)
        bT[j][kb] = *(const bf16x8*)(ldsRdB + ofs + (j * 2 + kb) * 1024);
#pragma unroll
    for (int kb = 0; kb < 2; ++kb)
#pragma unroll
      for (int i = 0; i < 4; ++i)
#pragma unroll
        for (int j = 0; j < 2; ++j)
          acc[i][j] = __builtin_amdgcn_mfma_f32_32x32x16_bf16(
              aT[i][kb], bT[j][kb], acc[i][j], 0, 0, 0);
  }

  // Epilogue: 32x32 C/D layout col=lane&31, row=(reg&3)+8*(reg>>2)+4*(lane>>5).
  const int colL = lane & 31;
  const int hi = lane >> 5;
  const int m0 = tm << 8;
  const int n0 = tn << 8;
#pragma unroll
  for (int j = 0; j < 2; ++j) {
    const int n = n0 + wn * 64 + j * 32 + colL;
    const float bvs = bias[n];
#pragma unroll
    for (int i = 0; i < 4; ++i) {
      const int rowb = m0 + wm * 128 + i * 32 + hi * 4;
#pragma unroll
      for (int q = 0; q < 4; ++q)
#pragma unroll
        for (int r = 0; r < 4; ++r)
          Out[(size_t)(rowb + q * 8 + r) * N + n] = acc[i][j][q * 4 + r] + bvs;
    }
  }
}

// ===========================================================================
// Fallback paths (P2 / P3) — 16x16x32 row-major kernels, unchanged.
// ===========================================================================
#define BM 128
#define BN 128
#define BK 32

__global__ void foldcast_w_kernel(const float* __restrict__ W,
                                  const float* __restrict__ A,   // [R,K]
                                  const float* __restrict__ Bl,  // [N,R]
                                  __hip_bfloat16* __restrict__ Wp, int K) {
  const int n = blockIdx.y;
  const int k = blockIdx.x * 256 + threadIdx.x;
  float acc = W[(size_t)n * K + k];
#pragma unroll
  for (int r = 0; r < LORA_R; ++r)
    acc += 2.0f * Bl[n * LORA_R + r] * A[(size_t)r * K + k];
  Wp[(size_t)n * K + k] = __float2bfloat16(acc);
}

__global__ void padb32_kernel(const float* __restrict__ lB,
                              __hip_bfloat16* __restrict__ B32) {
  const int i = blockIdx.x * 256 + threadIdx.x;  // over N*32
  const int n = i >> 5, r = i & 31;
  B32[i] = (r < LORA_R) ? __float2bfloat16(lB[n * LORA_R + r])
                        : __float2bfloat16(0.0f);
}

__global__ __launch_bounds__(256) void xa_fp32_kernel(
    const float* __restrict__ X, const float* __restrict__ A,
    __hip_bfloat16* __restrict__ XA32, int K) {
  const int lane = threadIdx.x & 63;
  const int m = blockIdx.x * 4 + (threadIdx.x >> 6);
  float acc[LORA_R] = {};
  const size_t xrow = (size_t)m * K;
  for (int k0 = 0; k0 < K; k0 += 256) {
    const int k = k0 + lane * 4;
    f32x4 xv = *(const f32x4*)(X + xrow + k);
#pragma unroll
    for (int r = 0; r < LORA_R; ++r) {
      f32x4 av = *(const f32x4*)(A + (size_t)r * K + k);
      acc[r] += xv[0] * av[0] + xv[1] * av[1] + xv[2] * av[2] + xv[3] * av[3];
    }
  }
#pragma unroll
  for (int r = 0; r < LORA_R; ++r)
    for (int off = 32; off > 0; off >>= 1) acc[r] += __shfl_xor(acc[r], off, 64);
  if (lane == 0) {
#pragma unroll
    for (int r = 0; r < LORA_R; ++r)
      XA32[(size_t)m * 32 + r] = __float2bfloat16(acc[r]);
#pragma unroll
    for (int r = LORA_R; r < 32; ++r)
      XA32[(size_t)m * 32 + r] = __float2bfloat16(0.0f);
  }
}

template <bool XPRE, bool WPRE, bool ELORA>
__global__ __launch_bounds__(256) void gemm_kernel(
    const void* __restrict__ Xv, const void* __restrict__ Wv,
    const float* __restrict__ bias,
    const __hip_bfloat16* __restrict__ XA32,  // [M,32] zero-padded (ELORA)
    const __hip_bfloat16* __restrict__ B32,   // [N,32] zero-padded (ELORA)
    float* __restrict__ Out, int M, int N, int K) {
  __shared__ __align__(16) unsigned short As[BM * BK];
  __shared__ __align__(16) unsigned short Bs[BN * BK];

  const int t = threadIdx.x;
  const int lane = t & 63;
  const int wave = t >> 6;
  const int m0 = blockIdx.y * BM;
  const int n0 = blockIdx.x * BN;
  const int wm = (wave >> 1) * 64;
  const int wn = (wave & 1) * 64;

  const int srow = t >> 2;
  const int ka = (t & 3) * 8;
  const int f_r = t >> 3;
  const int f_c = (t & 7) * 4;

  char* smA = (char*)As;
  char* smB = (char*)Bs;
  const int waveByte = wave * 1024;

  f32x4 acc[4][4];
#pragma unroll
  for (int mi = 0; mi < 4; ++mi)
#pragma unroll
    for (int ni = 0; ni < 4; ++ni) acc[mi][ni] = (f32x4){0.f, 0.f, 0.f, 0.f};

  const unsigned short* aBase = As + (wm + (lane & 15)) * BK + (lane >> 4) * 8;
  const unsigned short* bBase = Bs + (wn + (lane & 15)) * BK + (lane >> 4) * 8;

  const int kIters = K / BK;
  for (int kt = 0; kt < kIters; ++kt) {
    const int gk = kt * BK;
    if constexpr (XPRE) {
      const __hip_bfloat16* Xb = (const __hip_bfloat16*)Xv;
      async_copy16(Xb + (size_t)(m0 + srow) * K + gk + ka, smA + waveByte);
      async_copy16(Xb + (size_t)(m0 + 64 + srow) * K + gk + ka, smA + 4096 + waveByte);
    } else {
      const float* Xf = (const float*)Xv;
#pragma unroll
      for (int j = 0; j < 4; ++j) {
        const int row = j * 32 + f_r;
        f32x4 v = *(const f32x4*)(Xf + (size_t)(m0 + row) * K + gk + f_c);
        bf16x4 p;
#pragma unroll
        for (int e = 0; e < 4; ++e) p[e] = (__bf16)v[e];
        *(bf16x4*)(smA + row * 64 + f_c * 2) = p;
      }
    }
    if constexpr (WPRE) {
      const __hip_bfloat16* Wb = (const __hip_bfloat16*)Wv;
      async_copy16(Wb + (size_t)(n0 + srow) * K + gk + ka, smB + waveByte);
      async_copy16(Wb + (size_t)(n0 + 64 + srow) * K + gk + ka, smB + 4096 + waveByte);
    } else {
      const float* Wf = (const float*)Wv;
#pragma unroll
      for (int j = 0; j < 4; ++j) {
        const int row = j * 32 + f_r;
        f32x4 v = *(const f32x4*)(Wf + (size_t)(n0 + row) * K + gk + f_c);
        bf16x4 p;
#pragma unroll
        for (int e = 0; e < 4; ++e) p[e] = (__bf16)v[e];
        *(bf16x4*)(smB + row * 64 + f_c * 2) = p;
      }
    }
    __syncthreads();

    bf16x8 af[4], bfv[4];
#pragma unroll
    for (int i = 0; i < 4; ++i) {
      af[i] = *(const bf16x8*)(aBase + i * 16 * BK);
      bfv[i] = *(const bf16x8*)(bBase + i * 16 * BK);
    }
#pragma unroll
    for (int mi = 0; mi < 4; ++mi)
#pragma unroll
      for (int ni = 0; ni < 4; ++ni)
        acc[mi][ni] = __builtin_amdgcn_mfma_f32_16x16x32_bf16(
            af[mi], bfv[ni], acc[mi][ni], 0, 0, 0);
    __syncthreads();
  }

  const int col = lane & 15;
  const int quad = lane >> 4;
  const int rbase = quad * 4;

  bf16x8 xaf[4], blf[4];
  if constexpr (ELORA) {
#pragma unroll
    for (int mi = 0; mi < 4; ++mi)
      xaf[mi] = *(const bf16x8*)(XA32 + (size_t)(m0 + wm + mi * 16 + col) * 32 + quad * 8);
#pragma unroll
    for (int ni = 0; ni < 4; ++ni)
      blf[ni] = *(const bf16x8*)(B32 + (size_t)(n0 + wn + ni * 16 + col) * 32 + quad * 8);
  }

  const f32x4 zero4 = (f32x4){0.f, 0.f, 0.f, 0.f};
#pragma unroll
  for (int ni = 0; ni < 4; ++ni) {
    const int n = n0 + wn + ni * 16 + col;
    const float bv = bias[n];
#pragma unroll
    for (int mi = 0; mi < 4; ++mi) {
      f32x4 u = zero4;
      if constexpr (ELORA)
        u = __builtin_amdgcn_mfma_f32_16x16x32_bf16(xaf[mi], blf[ni], zero4, 0, 0, 0);
      const size_t rowBase = (size_t)(m0 + wm + mi * 16 + rbase) * N + n;
#pragma unroll
      for (int r = 0; r < 4; ++r)
        Out[rowBase + (size_t)r * N] = acc[mi][ni][r] + bv + 2.0f * u[r];
    }
  }
}

// ---------------------------------------------------------------------------
extern "C" void kernel_launch(void* const* d_in, const int* in_sizes, int n_in,
                              void* d_out, int out_size, void* d_ws, size_t ws_size,
                              hipStream_t stream) {
  const float* X    = (const float*)d_in[0];  // [B,S,Din] fp32
  const float* W    = (const float*)d_in[1];  // [Dout,Din] fp32
  const float* bias = (const float*)d_in[2];  // [Dout] fp32
  const float* lA   = (const float*)d_in[3];  // [R,Din] fp32
  const float* lB   = (const float*)d_in[4];  // [Dout,R] fp32
  float* Out = (float*)d_out;

  const int K = in_sizes[3] / LORA_R;  // 4096
  const int N = in_sizes[2];           // 4096
  const int M = in_sizes[0] / K;       // 8192

  const size_t xbBytes = (size_t)M * K * 2;  // 67,108,864
  const size_t wpBytes = (size_t)N * K * 2;  // 33,554,432

  if (ws_size >= xbBytes + wpBytes) {
    // P1: packed precast X and fold+cast W', pipelined 256^2 GEMM (32x32x16).
    __hip_bfloat16* Xp = (__hip_bfloat16*)d_ws;
    __hip_bfloat16* Wq = (__hip_bfloat16*)((char*)d_ws + xbBytes);
    pack_x_kernel<<<dim3(K / 64, M / 32), 256, 0, stream>>>(X, Xp, K);
    foldpack_w_kernel<<<dim3(K / 64, N / 32), 256, 0, stream>>>(W, lA, lB, Wq, K);
    gemm_pipelined<<<dim3((M / 256) * (N / 256)), 512, 0, stream>>>(
        Xp, Wq, bias, Out, M, N, K);
  } else if (ws_size >= wpBytes) {
    // P2: fold+cast W' only (row-major); convert X tiles in-kernel.
    __hip_bfloat16* Wp = (__hip_bfloat16*)d_ws;
    foldcast_w_kernel<<<dim3(K / 256, N), 256, 0, stream>>>(W, lA, lB, Wp, K);
    gemm_kernel<false, true, false><<<dim3(N / BN, M / BM), 256, 0, stream>>>(
        X, Wp, bias, nullptr, nullptr, Out, M, N, K);
  } else {
    // P3: tiny ws — LoRA via epilogue MFMA, both operands converted in-kernel.
    __hip_bfloat16* XA32 = (__hip_bfloat16*)d_ws;           // M*32*2 = 512 KB
    __hip_bfloat16* B32  = XA32 + (size_t)M * 32;           // N*32*2 = 256 KB
    padb32_kernel<<<dim3((N * 32) / 256), 256, 0, stream>>>(lB, B32);
    xa_fp32_kernel<<<dim3(M / 4), 256, 0, stream>>>(X, lA, XA32, K);
    gemm_kernel<false, false, true><<<dim3(N / BN, M / BM), 256, 0, stream>>>(
        X, W, bias, XA32, B32, Out, M, N, K);
  }
}

// Round 4
// 520.424 us; speedup vs baseline: 1.0369x; 1.0369x over previous
//
#include <hip/hip_runtime.h>
#include <hip/hip_bf16.h>
#include <stdint.h>

// ---------------------------------------------------------------------------
// LoRALinear (fp32 in / fp32 out):
//   C[M,N] = X[M,K] @ W[N,K]^T + bias[N] + 2.0 * (X @ A[R,K]^T) @ B[N,R]^T
// M=8192, N=4096, K=4096, R=16.
//
// Round-7: revert round-6's 32x32 experiment (regressed: FETCH 295->435 MB,
// 269 us). Back to the proven round-5 base (16x16x32, packed 16x32 blocks,
// 246 us, MfmaUtil 50%) with ONE schedule change: round-5 paid 2 sync points
// per K-tile around 16-MFMA clusters; wall/tile 2311 cyc vs MFMA floor 1242.
// Now: ONE barrier per K-tile around a 32-MFMA cluster, full tile-parity
// register double-buffer (12 ds_read_b128 per set), counted lgkmcnt(12)
// (old set done, new set in flight), vmcnt(4) before the single barrier
// (guarantees tile t+2 landed at end of body t; body t+1 reads t+2's frags).
// 4-deep LDS circular buffers, distance-3 staging, XCD swizzle unchanged.
// ---------------------------------------------------------------------------

typedef __bf16 bf16x8 __attribute__((ext_vector_type(8)));
typedef __bf16 bf16x4 __attribute__((ext_vector_type(4)));
typedef float f32x4 __attribute__((ext_vector_type(4)));

#define LORA_R 16

__device__ __forceinline__ void async_copy16(const void* g, void* l) {
  __builtin_amdgcn_global_load_lds(
      (const __attribute__((address_space(1))) void*)g,
      (__attribute__((address_space(3))) void*)l, 16, 0, 0);
}

// ---------------------------------------------------------------------------
// Packed operand layout: 16x32 blocks, block (rb,kb) at (rb*(K/32)+kb)*1024 B.
// Lane l's 16 B = row rb*16+(l&15), k = kb*32+(l>>4)*8 .. +7  (MFMA A/B frag).
// ---------------------------------------------------------------------------
__global__ __launch_bounds__(256) void pack_x_kernel(
    const float* __restrict__ X, __hip_bfloat16* __restrict__ Xp, int K) {
  const int lane = threadIdx.x & 63;
  const int wave = threadIdx.x >> 6;
  const int nkb = K >> 5;
  const int kb = blockIdx.x * 4 + wave;
  const int mb = blockIdx.y;
  const int row = (mb << 4) + (lane & 15);
  const int col = (kb << 5) + ((lane >> 4) << 3);
  const float* src = X + (size_t)row * K + col;
  f32x4 v0 = *(const f32x4*)src;
  f32x4 v1 = *(const f32x4*)(src + 4);
  bf16x8 o;
#pragma unroll
  for (int j = 0; j < 4; ++j) { o[j] = (__bf16)v0[j]; o[4 + j] = (__bf16)v1[j]; }
  *(bf16x8*)((char*)Xp + ((size_t)(mb * nkb + kb) << 10) + (lane << 4)) = o;
}

__global__ __launch_bounds__(256) void foldpack_w_kernel(
    const float* __restrict__ W, const float* __restrict__ A,
    const float* __restrict__ Bl, __hip_bfloat16* __restrict__ Wp, int K) {
  const int lane = threadIdx.x & 63;
  const int wave = threadIdx.x >> 6;
  const int nkb = K >> 5;
  const int kb = blockIdx.x * 4 + wave;
  const int nb = blockIdx.y;
  const int n = (nb << 4) + (lane & 15);
  const int col = (kb << 5) + ((lane >> 4) << 3);
  float res[8];
  {
    f32x4 w0 = *(const f32x4*)(W + (size_t)n * K + col);
    f32x4 w1 = *(const f32x4*)(W + (size_t)n * K + col + 4);
#pragma unroll
    for (int j = 0; j < 4; ++j) { res[j] = w0[j]; res[4 + j] = w1[j]; }
  }
#pragma unroll
  for (int r = 0; r < LORA_R; ++r) {
    const float b2 = 2.0f * Bl[n * LORA_R + r];  // SCALING = 2.0
    f32x4 a0 = *(const f32x4*)(A + (size_t)r * K + col);
    f32x4 a1 = *(const f32x4*)(A + (size_t)r * K + col + 4);
#pragma unroll
    for (int j = 0; j < 4; ++j) { res[j] += b2 * a0[j]; res[4 + j] += b2 * a1[j]; }
  }
  bf16x8 o;
#pragma unroll
  for (int j = 0; j < 8; ++j) o[j] = (__bf16)res[j];
  *(bf16x8*)((char*)Wp + ((size_t)(nb * nkb + kb) << 10) + (lane << 4)) = o;
}

// ---------------------------------------------------------------------------
// Pipelined 256x256 GEMM, 8 waves (2M x 4N), per-wave 128x64, BK=32.
// One barrier per K-tile; 32 MFMA per cluster; E/O register double-buffer.
// ---------------------------------------------------------------------------
#define STAGE_A(T, SLOT)                                                      \
  async_copy16(aSrc + ((size_t)(T) << 10), ldsA + (SLOT));                    \
  async_copy16(aSrc + siteStride + ((size_t)(T) << 10), ldsA + (SLOT) + 8192);

#define STAGE_B(T, SLOT)                                                      \
  async_copy16(bSrc + ((size_t)(T) << 10), ldsB + (SLOT));                    \
  async_copy16(bSrc + siteStride + ((size_t)(T) << 10), ldsB + (SLOT) + 8192);

#define SBAR() __builtin_amdgcn_sched_barrier(0)

// Body for K-tile T: consume (AC,BC); read tile T+1 into (AN,BN);
// stage tile T+3; lgkm(12) = old set done; 32 MFMA; vmcnt(4); barrier.
#define BODY(AC, BC, AN, BN, T)                                               \
  {                                                                           \
    const int _ofsN = (((T) + 1) & 3) << 15;                                  \
    const int _s3 = (((T) + 3) & 3) << 15;                                    \
    _Pragma("unroll")                                                         \
    for (int _i = 0; _i < 8; ++_i)                                            \
      AN[_i] = *(const bf16x8*)(ldsRdA + _ofsN + (_i << 10));                 \
    _Pragma("unroll")                                                         \
    for (int _j = 0; _j < 4; ++_j)                                            \
      BN[_j] = *(const bf16x8*)(ldsRdB + _ofsN + (_j << 10));                 \
    STAGE_A((T) + 3, _s3);                                                    \
    STAGE_B((T) + 3, _s3);                                                    \
    asm volatile("s_waitcnt lgkmcnt(12)" ::: "memory");                       \
    SBAR();                                                                   \
    __builtin_amdgcn_s_setprio(1);                                            \
    _Pragma("unroll")                                                         \
    for (int _mi = 0; _mi < 8; ++_mi)                                         \
      _Pragma("unroll")                                                       \
      for (int _ni = 0; _ni < 4; ++_ni)                                       \
        acc[_mi][_ni] = __builtin_amdgcn_mfma_f32_16x16x32_bf16(              \
            AC[_mi], BC[_ni], acc[_mi][_ni], 0, 0, 0);                        \
    __builtin_amdgcn_s_setprio(0);                                            \
    asm volatile("s_waitcnt vmcnt(4)" ::: "memory");                          \
    __builtin_amdgcn_s_barrier();                                             \
    SBAR();                                                                   \
  }

__global__ __launch_bounds__(512, 2) void gemm_pipelined(
    const __hip_bfloat16* __restrict__ Xp,  // packed [M/16][K/32] blocks
    const __hip_bfloat16* __restrict__ Wp,  // packed [N/16][K/32] blocks
    const float* __restrict__ bias,
    float* __restrict__ Out, int M, int N, int K) {
  __shared__ __align__(16) char lds[131072];

  const int tid = threadIdx.x;
  const int lane = tid & 63;
  const int wave = tid >> 6;
  const int wm = wave >> 2;  // 0..1
  const int wn = wave & 3;   // 0..3

  // Bijective XCD-aware swizzle (gridDim.x = 512, % 8 == 0).
  const int nwg = gridDim.x;
  const int bid = blockIdx.x;
  const int swz = (bid & 7) * (nwg >> 3) + (bid >> 3);
  const int ntn = N >> 8;  // 16
  const int tm = swz / ntn;
  const int tn = swz - tm * ntn;

  const int nkb = K >> 5;  // 128 K-tiles
  const int nt = nkb;

  const char* aSrc = (const char*)Xp +
      ((size_t)((tm << 4) + wave) * nkb << 10) + (lane << 4);
  const char* bSrc = (const char*)Wp +
      ((size_t)((tn << 4) + wave) * nkb << 10) + (lane << 4);
  const size_t siteStride = (size_t)8 * nkb << 10;

  char* ldsA = lds + (wave << 10);
  char* ldsB = lds + 16384 + (wave << 10);
  const char* ldsRdA = lds + (wm << 13) + (lane << 4);
  const char* ldsRdB = lds + 16384 + (wn << 12) + (lane << 4);

  f32x4 acc[8][4];
#pragma unroll
  for (int i = 0; i < 8; ++i)
#pragma unroll
    for (int j = 0; j < 4; ++j) acc[i][j] = (f32x4){0.f, 0.f, 0.f, 0.f};

  // Prologue: stage tiles 0,1,2 into bufs 0,1,2 (12 loads/wave).
#pragma unroll
  for (int pt = 0; pt < 3; ++pt) {
    const int bo = pt << 15;
    STAGE_A(pt, bo);
    STAGE_B(pt, bo);
  }
  // Tiles 0 AND 1 landed (body 0 issues ds_reads of tile 1 immediately).
  asm volatile("s_waitcnt vmcnt(4)" ::: "memory");
  __builtin_amdgcn_s_barrier();
  SBAR();

  bf16x8 aE[8], bE[4], aO[8], bO[4];
  // Preload tile 0 into E set.
#pragma unroll
  for (int i = 0; i < 8; ++i) aE[i] = *(const bf16x8*)(ldsRdA + (i << 10));
#pragma unroll
  for (int j = 0; j < 4; ++j) bE[j] = *(const bf16x8*)(ldsRdB + (j << 10));

  for (int t = 0; t + 5 <= nt; t += 2) {
    BODY(aE, bE, aO, bO, t);
    BODY(aO, bO, aE, bE, t + 1);
  }

  // Drain: stage last tile, full drain, compute tiles nt-4..nt-1 plainly.
  {
    const int tL = nt - 1;
    const int sL = (tL & 3) << 15;
    STAGE_A(tL, sL);
    STAGE_B(tL, sL);
    asm volatile("s_waitcnt vmcnt(0)" ::: "memory");
    __builtin_amdgcn_s_barrier();
    SBAR();
    for (int t = nt - 4; t < nt; ++t) {
      const int ofs = (t & 3) << 15;
      bf16x8 aT[8], bT[4];
#pragma unroll
      for (int i = 0; i < 8; ++i)
        aT[i] = *(const bf16x8*)(ldsRdA + ofs + (i << 10));
#pragma unroll
      for (int j = 0; j < 4; ++j)
        bT[j] = *(const bf16x8*)(ldsRdB + ofs + (j << 10));
#pragma unroll
      for (int mi = 0; mi < 8; ++mi)
#pragma unroll
        for (int ni = 0; ni < 4; ++ni)
          acc[mi][ni] = __builtin_amdgcn_mfma_f32_16x16x32_bf16(
              aT[mi], bT[ni], acc[mi][ni], 0, 0, 0);
    }
  }

  // Epilogue: C/D layout col=lane&15, row=(lane>>4)*4+reg.
  const int col = lane & 15;
  const int quad = lane >> 4;
  const int m0 = tm << 8;
  const int n0 = tn << 8;
#pragma unroll
  for (int ni = 0; ni < 4; ++ni) {
    const int n = n0 + wn * 64 + ni * 16 + col;
    const float bvs = bias[n];
#pragma unroll
    for (int mi = 0; mi < 8; ++mi) {
      const size_t rowBase = (size_t)(m0 + wm * 128 + mi * 16 + quad * 4) * N + n;
#pragma unroll
      for (int r = 0; r < 4; ++r)
        Out[rowBase + (size_t)r * N] = acc[mi][ni][r] + bvs;
    }
  }
}

// ===========================================================================
// Fallback paths (P2 / P3), unchanged.
// ===========================================================================
#define BM 128
#define BN 128
#define BK 32

__global__ void foldcast_w_kernel(const float* __restrict__ W,
                                  const float* __restrict__ A,   // [R,K]
                                  const float* __restrict__ Bl,  // [N,R]
                                  __hip_bfloat16* __restrict__ Wp, int K) {
  const int n = blockIdx.y;
  const int k = blockIdx.x * 256 + threadIdx.x;
  float acc = W[(size_t)n * K + k];
#pragma unroll
  for (int r = 0; r < LORA_R; ++r)
    acc += 2.0f * Bl[n * LORA_R + r] * A[(size_t)r * K + k];
  Wp[(size_t)n * K + k] = __float2bfloat16(acc);
}

__global__ void padb32_kernel(const float* __restrict__ lB,
                              __hip_bfloat16* __restrict__ B32) {
  const int i = blockIdx.x * 256 + threadIdx.x;  // over N*32
  const int n = i >> 5, r = i & 31;
  B32[i] = (r < LORA_R) ? __float2bfloat16(lB[n * LORA_R + r])
                        : __float2bfloat16(0.0f);
}

__global__ __launch_bounds__(256) void xa_fp32_kernel(
    const float* __restrict__ X, const float* __restrict__ A,
    __hip_bfloat16* __restrict__ XA32, int K) {
  const int lane = threadIdx.x & 63;
  const int m = blockIdx.x * 4 + (threadIdx.x >> 6);
  float acc[LORA_R] = {};
  const size_t xrow = (size_t)m * K;
  for (int k0 = 0; k0 < K; k0 += 256) {
    const int k = k0 + lane * 4;
    f32x4 xv = *(const f32x4*)(X + xrow + k);
#pragma unroll
    for (int r = 0; r < LORA_R; ++r) {
      f32x4 av = *(const f32x4*)(A + (size_t)r * K + k);
      acc[r] += xv[0] * av[0] + xv[1] * av[1] + xv[2] * av[2] + xv[3] * av[3];
    }
  }
#pragma unroll
  for (int r = 0; r < LORA_R; ++r)
    for (int off = 32; off > 0; off >>= 1) acc[r] += __shfl_xor(acc[r], off, 64);
  if (lane == 0) {
#pragma unroll
    for (int r = 0; r < LORA_R; ++r)
      XA32[(size_t)m * 32 + r] = __float2bfloat16(acc[r]);
#pragma unroll
    for (int r = LORA_R; r < 32; ++r)
      XA32[(size_t)m * 32 + r] = __float2bfloat16(0.0f);
  }
}

template <bool XPRE, bool WPRE, bool ELORA>
__global__ __launch_bounds__(256) void gemm_kernel(
    const void* __restrict__ Xv, const void* __restrict__ Wv,
    const float* __restrict__ bias,
    const __hip_bfloat16* __restrict__ XA32,  // [M,32] zero-padded (ELORA)
    const __hip_bfloat16* __restrict__ B32,   // [N,32] zero-padded (ELORA)
    float* __restrict__ Out, int M, int N, int K) {
  __shared__ __align__(16) unsigned short As[BM * BK];
  __shared__ __align__(16) unsigned short Bs[BN * BK];

  const int t = threadIdx.x;
  const int lane = t & 63;
  const int wave = t >> 6;
  const int m0 = blockIdx.y * BM;
  const int n0 = blockIdx.x * BN;
  const int wm = (wave >> 1) * 64;
  const int wn = (wave & 1) * 64;

  const int srow = t >> 2;
  const int ka = (t & 3) * 8;
  const int f_r = t >> 3;
  const int f_c = (t & 7) * 4;

  char* smA = (char*)As;
  char* smB = (char*)Bs;
  const int waveByte = wave * 1024;

  f32x4 acc[4][4];
#pragma unroll
  for (int mi = 0; mi < 4; ++mi)
#pragma unroll
    for (int ni = 0; ni < 4; ++ni) acc[mi][ni] = (f32x4){0.f, 0.f, 0.f, 0.f};

  const unsigned short* aBase = As + (wm + (lane & 15)) * BK + (lane >> 4) * 8;
  const unsigned short* bBase = Bs + (wn + (lane & 15)) * BK + (lane >> 4) * 8;

  const int kIters = K / BK;
  for (int kt = 0; kt < kIters; ++kt) {
    const int gk = kt * BK;
    if constexpr (XPRE) {
      const __hip_bfloat16* Xb = (const __hip_bfloat16*)Xv;
      async_copy16(Xb + (size_t)(m0 + srow) * K + gk + ka, smA + waveByte);
      async_copy16(Xb + (size_t)(m0 + 64 + srow) * K + gk + ka, smA + 4096 + waveByte);
    } else {
      const float* Xf = (const float*)Xv;
#pragma unroll
      for (int j = 0; j < 4; ++j) {
        const int row = j * 32 + f_r;
        f32x4 v = *(const f32x4*)(Xf + (size_t)(m0 + row) * K + gk + f_c);
        bf16x4 p;
#pragma unroll
        for (int e = 0; e < 4; ++e) p[e] = (__bf16)v[e];
        *(bf16x4*)(smA + row * 64 + f_c * 2) = p;
      }
    }
    if constexpr (WPRE) {
      const __hip_bfloat16* Wb = (const __hip_bfloat16*)Wv;
      async_copy16(Wb + (size_t)(n0 + srow) * K + gk + ka, smB + waveByte);
      async_copy16(Wb + (size_t)(n0 + 64 + srow) * K + gk + ka, smB + 4096 + waveByte);
    } else {
      const float* Wf = (const float*)Wv;
#pragma unroll
      for (int j = 0; j < 4; ++j) {
        const int row = j * 32 + f_r;
        f32x4 v = *(const f32x4*)(Wf + (size_t)(n0 + row) * K + gk + f_c);
        bf16x4 p;
#pragma unroll
        for (int e = 0; e < 4; ++e) p[e] = (__bf16)v[e];
        *(bf16x4*)(smB + row * 64 + f_c * 2) = p;
      }
    }
    __syncthreads();

    bf16x8 af[4], bfv[4];
#pragma unroll
    for (int i = 0; i < 4; ++i) {
      af[i] = *(const bf16x8*)(aBase + i * 16 * BK);
      bfv[i] = *(const bf16x8*)(bBase + i * 16 * BK);
    }
#pragma unroll
    for (int mi = 0; mi < 4; ++mi)
#pragma unroll
      for (int ni = 0; ni < 4; ++ni)
        acc[mi][ni] = __builtin_amdgcn_mfma_f32_16x16x32_bf16(
            af[mi], bfv[ni], acc[mi][ni], 0, 0, 0);
    __syncthreads();
  }

  const int col = lane & 15;
  const int quad = lane >> 4;
  const int rbase = quad * 4;

  bf16x8 xaf[4], blf[4];
  if constexpr (ELORA) {
#pragma unroll
    for (int mi = 0; mi < 4; ++mi)
      xaf[mi] = *(const bf16x8*)(XA32 + (size_t)(m0 + wm + mi * 16 + col) * 32 + quad * 8);
#pragma unroll
    for (int ni = 0; ni < 4; ++ni)
      blf[ni] = *(const bf16x8*)(B32 + (size_t)(n0 + wn + ni * 16 + col) * 32 + quad * 8);
  }

  const f32x4 zero4 = (f32x4){0.f, 0.f, 0.f, 0.f};
#pragma unroll
  for (int ni = 0; ni < 4; ++ni) {
    const int n = n0 + wn + ni * 16 + col;
    const float bv = bias[n];
#pragma unroll
    for (int mi = 0; mi < 4; ++mi) {
      f32x4 u = zero4;
      if constexpr (ELORA)
        u = __builtin_amdgcn_mfma_f32_16x16x32_bf16(xaf[mi], blf[ni], zero4, 0, 0, 0);
      const size_t rowBase = (size_t)(m0 + wm + mi * 16 + rbase) * N + n;
#pragma unroll
      for (int r = 0; r < 4; ++r)
        Out[rowBase + (size_t)r * N] = acc[mi][ni][r] + bv + 2.0f * u[r];
    }
  }
}

// ---------------------------------------------------------------------------
extern "C" void kernel_launch(void* const* d_in, const int* in_sizes, int n_in,
                              void* d_out, int out_size, void* d_ws, size_t ws_size,
                              hipStream_t stream) {
  const float* X    = (const float*)d_in[0];  // [B,S,Din] fp32
  const float* W    = (const float*)d_in[1];  // [Dout,Din] fp32
  const float* bias = (const float*)d_in[2];  // [Dout] fp32
  const float* lA   = (const float*)d_in[3];  // [R,Din] fp32
  const float* lB   = (const float*)d_in[4];  // [Dout,R] fp32
  float* Out = (float*)d_out;

  const int K = in_sizes[3] / LORA_R;  // 4096
  const int N = in_sizes[2];           // 4096
  const int M = in_sizes[0] / K;       // 8192

  const size_t xbBytes = (size_t)M * K * 2;  // 67,108,864
  const size_t wpBytes = (size_t)N * K * 2;  // 33,554,432

  if (ws_size >= xbBytes + wpBytes) {
    // P1: packed precast X and fold+cast W', pipelined 256^2 GEMM.
    __hip_bfloat16* Xp = (__hip_bfloat16*)d_ws;
    __hip_bfloat16* Wq = (__hip_bfloat16*)((char*)d_ws + xbBytes);
    pack_x_kernel<<<dim3(K / 128, M / 16), 256, 0, stream>>>(X, Xp, K);
    foldpack_w_kernel<<<dim3(K / 128, N / 16), 256, 0, stream>>>(W, lA, lB, Wq, K);
    gemm_pipelined<<<dim3((M / 256) * (N / 256)), 512, 0, stream>>>(
        Xp, Wq, bias, Out, M, N, K);
  } else if (ws_size >= wpBytes) {
    // P2: fold+cast W' only (row-major); convert X tiles in-kernel.
    __hip_bfloat16* Wp = (__hip_bfloat16*)d_ws;
    foldcast_w_kernel<<<dim3(K / 256, N), 256, 0, stream>>>(W, lA, lB, Wp, K);
    gemm_kernel<false, true, false><<<dim3(N / BN, M / BM), 256, 0, stream>>>(
        X, Wp, bias, nullptr, nullptr, Out, M, N, K);
  } else {
    // P3: tiny ws — LoRA via epilogue MFMA, both operands converted in-kernel.
    __hip_bfloat16* XA32 = (__hip_bfloat16*)d_ws;           // M*32*2 = 512 KB
    __hip_bfloat16* B32  = XA32 + (size_t)M * 32;           // N*32*2 = 256 KB
    padb32_kernel<<<dim3((N * 32) / 256), 256, 0, stream>>>(lB, B32);
    xa_fp32_kernel<<<dim3(M / 4), 256, 0, stream>>>(X, lA, XA32, K);
    gemm_kernel<false, false, true><<<dim3(N / BN, M / BM), 256, 0, stream>>>(
        X, W, bias, XA32, B32, Out, M, N, K);
  }
}